// Round 2
// baseline (455.317 us; speedup 1.0000x reference)
//
#include <hip/hip_runtime.h>
#include <cstdint>

// BlockwiseWTA: per 512-elem block keep top-32 values, zero the rest.
// R2: one wave handles TWO 512-elem blocks (16 elems/lane). Branchless,
// fully-unrolled 32-step MSB-first threshold descent on order-preserving
// uint keys. Counting = 8 direct ballots + scalar popcount tree per block
// per step (VALU-cheap; SALU runs in parallel pipe). The greedy descent
// provably ends with T == exact 32nd-largest key, so tie handling is a
// one-shot epilogue (keep k>T plus first (32-a) of k==T by index).

__device__ __forceinline__ uint32_t fkey(float f) {
    uint32_t u = __float_as_uint(f);
    // order-preserving map: negatives -> ~u, positives -> u | signbit
    return (u & 0x80000000u) ? ~u : (u | 0x80000000u);
}

__device__ __forceinline__ float finv(uint32_t k) {
    uint32_t u = (k & 0x80000000u) ? (k ^ 0x80000000u) : ~k;
    return __uint_as_float(u);
}

__device__ __forceinline__ void emit_block(const uint32_t* k, uint32_t T,
                                           uint32_t lane, float4* o4,
                                           uint32_t idx0, uint32_t idx1) {
    bool keep[8];
    uint32_t aC = 0, eC = 0;
    uint64_t meq[8];
#pragma unroll
    for (int i = 0; i < 8; ++i) {
        meq[i] = __ballot(k[i] == T);
        aC += (uint32_t)__popcll(__ballot(k[i] > T));
        eC += (uint32_t)__popcll(meq[i]);
        keep[i] = (k[i] >= T);
    }
    if (aC + eC > 32u) {
        // Rare: duplicates of the threshold value straddle rank 32.
        // Keep first r = 32-aC of the ==T elements in element-index order.
        uint32_t r = 32u - aC;
        uint64_t below = (lane == 0) ? 0ull : (~0ull >> (64u - lane));
        // first half: element position 4*lane + i, i in 0..3
        uint32_t c0 = (uint32_t)(__popcll(meq[0] & below) + __popcll(meq[1] & below)
                               + __popcll(meq[2] & below) + __popcll(meq[3] & below));
        uint32_t e0 = (k[0] == T), e1 = (k[1] == T), e2 = (k[2] == T);
        uint32_t p0 = c0;
        uint32_t p1 = c0 + e0;
        uint32_t p2 = p1 + e1;
        uint32_t p3 = p2 + e2;
        uint32_t firstHalfEq = (uint32_t)(__popcll(meq[0]) + __popcll(meq[1])
                                        + __popcll(meq[2]) + __popcll(meq[3]));
        uint32_t c1 = (uint32_t)(__popcll(meq[4] & below) + __popcll(meq[5] & below)
                               + __popcll(meq[6] & below) + __popcll(meq[7] & below));
        uint32_t e4 = (k[4] == T), e5 = (k[5] == T), e6 = (k[6] == T);
        uint32_t p4 = firstHalfEq + c1;
        uint32_t p5 = p4 + e4;
        uint32_t p6 = p5 + e5;
        uint32_t p7 = p6 + e6;
        keep[0] = (k[0] > T) || ((k[0] == T) && (p0 < r));
        keep[1] = (k[1] > T) || ((k[1] == T) && (p1 < r));
        keep[2] = (k[2] > T) || ((k[2] == T) && (p2 < r));
        keep[3] = (k[3] > T) || ((k[3] == T) && (p3 < r));
        keep[4] = (k[4] > T) || ((k[4] == T) && (p4 < r));
        keep[5] = (k[5] > T) || ((k[5] == T) && (p5 < r));
        keep[6] = (k[6] > T) || ((k[6] == T) && (p6 < r));
        keep[7] = (k[7] > T) || ((k[7] == T) && (p7 < r));
    }
    float4 oa, ob;
    oa.x = keep[0] ? finv(k[0]) : 0.0f;
    oa.y = keep[1] ? finv(k[1]) : 0.0f;
    oa.z = keep[2] ? finv(k[2]) : 0.0f;
    oa.w = keep[3] ? finv(k[3]) : 0.0f;
    ob.x = keep[4] ? finv(k[4]) : 0.0f;
    ob.y = keep[5] ? finv(k[5]) : 0.0f;
    ob.z = keep[6] ? finv(k[6]) : 0.0f;
    ob.w = keep[7] ? finv(k[7]) : 0.0f;
    o4[idx0] = oa;
    o4[idx1] = ob;
}

__global__ __launch_bounds__(256) void wta_kernel(const float* __restrict__ x,
                                                  float* __restrict__ out) {
    const uint32_t wid = blockIdx.x * 4u + (threadIdx.x >> 6);
    const uint32_t lane = threadIdx.x & 63u;
    const size_t base = (size_t)wid * 1024u;  // two 512-elem blocks per wave

    const float4* in4 = reinterpret_cast<const float4*>(x + base);
    float4 a0 = in4[lane];
    float4 a1 = in4[lane + 64u];
    float4 b0 = in4[lane + 128u];
    float4 b1 = in4[lane + 192u];

    uint32_t kA[8] = {fkey(a0.x), fkey(a0.y), fkey(a0.z), fkey(a0.w),
                      fkey(a1.x), fkey(a1.y), fkey(a1.z), fkey(a1.w)};
    uint32_t kB[8] = {fkey(b0.x), fkey(b0.y), fkey(b0.z), fkey(b0.w),
                      fkey(b1.x), fkey(b1.y), fkey(b1.z), fkey(b1.w)};

    // Branchless greedy MSB-first descent: T ends as the exact 32nd-largest
    // key (max T with count(k >= T) >= 32). Two independent chains (A, B)
    // interleave for ILP; counts via direct ballots + scalar popcounts.
    uint32_t TA = 0u, TB = 0u;
#pragma unroll
    for (int b = 31; b >= 0; --b) {
        const uint32_t bit = 1u << b;
        const uint32_t cA = TA | bit;
        const uint32_t cB = TB | bit;
        uint32_t tA = 0u, tB = 0u;
#pragma unroll
        for (int i = 0; i < 8; ++i) tA += (uint32_t)__popcll(__ballot(kA[i] >= cA));
#pragma unroll
        for (int i = 0; i < 8; ++i) tB += (uint32_t)__popcll(__ballot(kB[i] >= cB));
        TA = (tA >= 32u) ? cA : TA;
        TB = (tB >= 32u) ? cB : TB;
    }

    float4* o4 = reinterpret_cast<float4*>(out + base);
    emit_block(kA, TA, lane, o4, lane, lane + 64u);
    emit_block(kB, TB, lane, o4, lane + 128u, lane + 192u);
}

extern "C" void kernel_launch(void* const* d_in, const int* in_sizes, int n_in,
                              void* d_out, int out_size, void* d_ws, size_t ws_size,
                              hipStream_t stream) {
    const float* x = (const float*)d_in[0];
    float* out = (float*)d_out;
    const int total = in_sizes[0];          // 16384 * 4096
    const int waves = total / 1024;         // one wave per TWO 512-elem blocks
    const int blocks = waves / 4;           // 256 threads = 4 waves per WG
    wta_kernel<<<blocks, 256, 0, stream>>>(x, out);
}

// Round 3
// 428.024 us; speedup vs baseline: 1.0638x; 1.0638x over previous
//
#include <hip/hip_runtime.h>
#include <cstdint>

// BlockwiseWTA: per 512-elem block keep top-32 values, zero the rest.
// R3: one wave per block (max memory concurrency). Early-exit MSB-first
// bitwise threshold descent (~13 avg steps) on order-preserving uint keys.
// Counting = 8 direct ballots + one s_bcnt1_b64 each (SALU stays ~50 us/CU,
// under the 81 us memory floor; SALU is 1-per-CU shared — R2's lesson).
// Tie handling only on the rare no-early-exit path. Nontemporal 16B I/O.

typedef float v4f __attribute__((ext_vector_type(4)));

__device__ __forceinline__ uint32_t fkey(float f) {
    uint32_t u = __float_as_uint(f);
    // order-preserving map: negatives -> ~u, positives -> u | signbit
    uint32_t m = (uint32_t)((int32_t)u >> 31);   // all-ones if negative
    return u ^ (m | 0x80000000u);
}

__global__ __launch_bounds__(256) void wta_kernel(const float* __restrict__ x,
                                                  float* __restrict__ out) {
    const uint32_t wid = blockIdx.x * 4u + (threadIdx.x >> 6);
    const uint32_t lane = threadIdx.x & 63u;
    const size_t base = (size_t)wid * 512u;

    const v4f* in4 = reinterpret_cast<const v4f*>(x + base);
    v4f a = __builtin_nontemporal_load(in4 + lane);         // elems 4*lane..
    v4f b = __builtin_nontemporal_load(in4 + lane + 64u);   // elems 256+4*lane..

    float v[8] = {a.x, a.y, a.z, a.w, b.x, b.y, b.z, b.w};
    uint32_t k[8];
#pragma unroll
    for (int i = 0; i < 8; ++i) k[i] = fkey(v[i]);

    // Greedy MSB-first descent: ends with T == exact 32nd-largest key.
    // Early exit when count(k >= cand) == 32 exactly (then keep = k>=T is
    // final, even with duplicates).
    uint32_t T = 0u;
    bool exact = false;
#pragma unroll 1
    for (int bpos = 31; bpos >= 0; --bpos) {
        const uint32_t cand = T | (1u << bpos);
        uint32_t total = 0;
#pragma unroll
        for (int i = 0; i < 8; ++i)
            total += (uint32_t)__popcll(__ballot(k[i] >= cand));
        if (total >= 32u) {
            T = cand;
            if (total == 32u) { exact = true; break; }
        }
    }

    bool keep[8];
#pragma unroll
    for (int i = 0; i < 8; ++i) keep[i] = (k[i] >= T);

    if (!exact) {
        // Full 32-bit descent finished: T is the exact 32nd-largest key but
        // duplicates of T may straddle rank 32. Keep k>T plus the first
        // r = 32 - count(>T) of the ==T elements in element-index order.
        uint32_t aC = 0, eC = 0;
        uint64_t meq[8];
#pragma unroll
        for (int i = 0; i < 8; ++i) {
            meq[i] = __ballot(k[i] == T);
            aC += (uint32_t)__popcll(__ballot(k[i] > T));
            eC += (uint32_t)__popcll(meq[i]);
        }
        if (aC + eC > 32u) {
            uint32_t r = 32u - aC;
            uint64_t below = (lane == 0) ? 0ull : (~0ull >> (64u - lane));
            // first half: element position 4*lane + i, i in 0..3
            uint32_t c0 = (uint32_t)(__popcll(meq[0] & below) + __popcll(meq[1] & below)
                                   + __popcll(meq[2] & below) + __popcll(meq[3] & below));
            uint32_t e0 = (k[0] == T), e1 = (k[1] == T), e2 = (k[2] == T);
            uint32_t p0 = c0;
            uint32_t p1 = c0 + e0;
            uint32_t p2 = p1 + e1;
            uint32_t p3 = p2 + e2;
            uint32_t firstHalfEq = (uint32_t)(__popcll(meq[0]) + __popcll(meq[1])
                                            + __popcll(meq[2]) + __popcll(meq[3]));
            uint32_t c1 = (uint32_t)(__popcll(meq[4] & below) + __popcll(meq[5] & below)
                                   + __popcll(meq[6] & below) + __popcll(meq[7] & below));
            uint32_t e4 = (k[4] == T), e5 = (k[5] == T), e6 = (k[6] == T);
            uint32_t p4 = firstHalfEq + c1;
            uint32_t p5 = p4 + e4;
            uint32_t p6 = p5 + e5;
            uint32_t p7 = p6 + e6;
            keep[0] = (k[0] > T) || ((k[0] == T) && (p0 < r));
            keep[1] = (k[1] > T) || ((k[1] == T) && (p1 < r));
            keep[2] = (k[2] > T) || ((k[2] == T) && (p2 < r));
            keep[3] = (k[3] > T) || ((k[3] == T) && (p3 < r));
            keep[4] = (k[4] > T) || ((k[4] == T) && (p4 < r));
            keep[5] = (k[5] > T) || ((k[5] == T) && (p5 < r));
            keep[6] = (k[6] > T) || ((k[6] == T) && (p6 < r));
            keep[7] = (k[7] > T) || ((k[7] == T) && (p7 < r));
        }
    }

    v4f oa, ob;
    oa.x = keep[0] ? v[0] : 0.0f;
    oa.y = keep[1] ? v[1] : 0.0f;
    oa.z = keep[2] ? v[2] : 0.0f;
    oa.w = keep[3] ? v[3] : 0.0f;
    ob.x = keep[4] ? v[4] : 0.0f;
    ob.y = keep[5] ? v[5] : 0.0f;
    ob.z = keep[6] ? v[6] : 0.0f;
    ob.w = keep[7] ? v[7] : 0.0f;
    v4f* o4 = reinterpret_cast<v4f*>(out + base);
    __builtin_nontemporal_store(oa, o4 + lane);
    __builtin_nontemporal_store(ob, o4 + lane + 64u);
}

extern "C" void kernel_launch(void* const* d_in, const int* in_sizes, int n_in,
                              void* d_out, int out_size, void* d_ws, size_t ws_size,
                              hipStream_t stream) {
    const float* x = (const float*)d_in[0];
    float* out = (float*)d_out;
    const int total = in_sizes[0];          // 16384 * 4096
    const int waves = total / 512;          // one wave per 512-elem block
    const int blocks = waves / 4;           // 256 threads = 4 waves per WG
    wta_kernel<<<blocks, 256, 0, stream>>>(x, out);
}

// Round 4
// 408.700 us; speedup vs baseline: 1.1141x; 1.0473x over previous
//
#include <hip/hip_runtime.h>
#include <cstdint>

// BlockwiseWTA: per 512-elem block keep top-32 values, zero the rest.
// R4: one wave per block. Fast-start threshold search: the rank-32 value of
// 512 N(0,1) samples is ~1.53 +- 0.09, so probe count(>=1.0) / count(>=2.0)
// first — 2 steps replacing the 9 sign+exponent descent steps — then do
// mantissa-bit MSB-first descent with early exit (avg ~8 steps). Exact
// full-descent fallback for any distribution. Tie handling (lower index
// wins, matching jax.lax.top_k) on the rare no-exact-exit path.
// Counting = 8 direct ballots + s_bcnt1_b64 each (R2/R3 lesson: SALU is one
// shared unit per CU; keep both pipes under the ~83 us memory floor).

typedef float v4f __attribute__((ext_vector_type(4)));

__device__ __forceinline__ uint32_t fkey(float f) {
    uint32_t u = __float_as_uint(f);
    // order-preserving map: negatives -> ~u, positives -> u | signbit
    uint32_t m = (uint32_t)((int32_t)u >> 31);   // all-ones if negative
    return u ^ (m | 0x80000000u);
}

__device__ __forceinline__ uint32_t wcount(const uint32_t* k, uint32_t cand) {
    uint32_t t = 0;
#pragma unroll
    for (int i = 0; i < 8; ++i)
        t += (uint32_t)__popcll(__ballot(k[i] >= cand));
    return t;
}

__global__ __launch_bounds__(256) void wta_kernel(const float* __restrict__ x,
                                                  float* __restrict__ out) {
    const uint32_t wid = blockIdx.x * 4u + (threadIdx.x >> 6);
    const uint32_t lane = threadIdx.x & 63u;
    const size_t base = (size_t)wid * 512u;

    const v4f* in4 = reinterpret_cast<const v4f*>(x + base);
    v4f a = __builtin_nontemporal_load(in4 + lane);         // elems 4*lane..
    v4f b = __builtin_nontemporal_load(in4 + lane + 64u);   // elems 256+4*lane..

    float v[8] = {a.x, a.y, a.z, a.w, b.x, b.y, b.z, b.w};
    uint32_t k[8];
#pragma unroll
    for (int i = 0; i < 8; ++i) k[i] = fkey(v[i]);

    // ---- Fast-start: locate threshold's top 9 bits in 2 probes ----
    // key(+1.0f) = 0xBF800000, key(+2.0f) = 0xC0000000.
    uint32_t T;
    int startbit;
    bool exact = false;
    const uint32_t c1 = wcount(k, 0xBF800000u);
    if (c1 == 32u) {
        T = 0xBF800000u; exact = true; startbit = -1;
    } else if (c1 > 32u) {
        const uint32_t c2 = wcount(k, 0xC0000000u);
        if (c2 == 32u) {
            T = 0xC0000000u; exact = true; startbit = -1;
        } else if (c2 < 32u) {
            // threshold in [1.0, 2.0): exactly the state the full bitwise
            // descent reaches after bits 31..23. Continue at mantissa.
            T = 0xBF800000u; startbit = 22;
        } else {
            // threshold >= 2.0: bit30 accepted; continue at bit 29.
            T = 0xC0000000u; startbit = 29;
        }
    } else {
        // threshold < 1.0: full descent from the top.
        T = 0u; startbit = 31;
    }

    // ---- Greedy MSB-first descent (ends at exact 32nd-largest key) ----
#pragma unroll 1
    for (int bpos = startbit; bpos >= 0 && !exact; --bpos) {
        const uint32_t cand = T | (1u << bpos);
        const uint32_t total = wcount(k, cand);
        if (total >= 32u) {
            T = cand;
            if (total == 32u) exact = true;
        }
    }

    bool keep[8];
#pragma unroll
    for (int i = 0; i < 8; ++i) keep[i] = (k[i] >= T);

    if (!exact) {
        // T is the exact 32nd-largest key but duplicates of T may straddle
        // rank 32. Keep k>T plus first r = 32-count(>T) of ==T by index.
        uint32_t aC = 0, eC = 0;
        uint64_t meq[8];
#pragma unroll
        for (int i = 0; i < 8; ++i) {
            meq[i] = __ballot(k[i] == T);
            aC += (uint32_t)__popcll(__ballot(k[i] > T));
            eC += (uint32_t)__popcll(meq[i]);
        }
        if (aC + eC > 32u) {
            uint32_t r = 32u - aC;
            uint64_t below = (lane == 0) ? 0ull : (~0ull >> (64u - lane));
            // first half: element position 4*lane + i, i in 0..3
            uint32_t c0 = (uint32_t)(__popcll(meq[0] & below) + __popcll(meq[1] & below)
                                   + __popcll(meq[2] & below) + __popcll(meq[3] & below));
            uint32_t e0 = (k[0] == T), e1 = (k[1] == T), e2 = (k[2] == T);
            uint32_t p0 = c0;
            uint32_t p1 = c0 + e0;
            uint32_t p2 = p1 + e1;
            uint32_t p3 = p2 + e2;
            uint32_t firstHalfEq = (uint32_t)(__popcll(meq[0]) + __popcll(meq[1])
                                            + __popcll(meq[2]) + __popcll(meq[3]));
            uint32_t c1b = (uint32_t)(__popcll(meq[4] & below) + __popcll(meq[5] & below)
                                    + __popcll(meq[6] & below) + __popcll(meq[7] & below));
            uint32_t e4 = (k[4] == T), e5 = (k[5] == T), e6 = (k[6] == T);
            uint32_t p4 = firstHalfEq + c1b;
            uint32_t p5 = p4 + e4;
            uint32_t p6 = p5 + e5;
            uint32_t p7 = p6 + e6;
            keep[0] = (k[0] > T) || ((k[0] == T) && (p0 < r));
            keep[1] = (k[1] > T) || ((k[1] == T) && (p1 < r));
            keep[2] = (k[2] > T) || ((k[2] == T) && (p2 < r));
            keep[3] = (k[3] > T) || ((k[3] == T) && (p3 < r));
            keep[4] = (k[4] > T) || ((k[4] == T) && (p4 < r));
            keep[5] = (k[5] > T) || ((k[5] == T) && (p5 < r));
            keep[6] = (k[6] > T) || ((k[6] == T) && (p6 < r));
            keep[7] = (k[7] > T) || ((k[7] == T) && (p7 < r));
        }
    }

    v4f oa, ob;
    oa.x = keep[0] ? v[0] : 0.0f;
    oa.y = keep[1] ? v[1] : 0.0f;
    oa.z = keep[2] ? v[2] : 0.0f;
    oa.w = keep[3] ? v[3] : 0.0f;
    ob.x = keep[4] ? v[4] : 0.0f;
    ob.y = keep[5] ? v[5] : 0.0f;
    ob.z = keep[6] ? v[6] : 0.0f;
    ob.w = keep[7] ? v[7] : 0.0f;
    v4f* o4 = reinterpret_cast<v4f*>(out + base);
    __builtin_nontemporal_store(oa, o4 + lane);
    __builtin_nontemporal_store(ob, o4 + lane + 64u);
}

extern "C" void kernel_launch(void* const* d_in, const int* in_sizes, int n_in,
                              void* d_out, int out_size, void* d_ws, size_t ws_size,
                              hipStream_t stream) {
    const float* x = (const float*)d_in[0];
    float* out = (float*)d_out;
    const int total = in_sizes[0];          // 16384 * 4096
    const int waves = total / 512;          // one wave per 512-elem block
    const int blocks = waves / 4;           // 256 threads = 4 waves per WG
    wta_kernel<<<blocks, 256, 0, stream>>>(x, out);
}